// Round 1
// baseline (216.527 us; speedup 1.0000x reference)
//
#include <hip/hip_runtime.h>

constexpr int H = 768, B = 4, L = 128, R = 48, D = 100;
constexpr int BL = B * L;          // 512
constexpr int P_SZ = BL * H;       // 393216

// d_out offsets (floats)
constexpr int OUT_FHS = 0, OUT_FHE = 512, OUT_FTS = 1024, OUT_FTE = 25600,
              OUT_BTS = 50176, OUT_BTE = 50688, OUT_BHS = 51200, OUT_BHE = 75776;

// workspace offsets (floats). P order: j=0..5 -> big_w {0,1,4,7,8,9}
constexpr int WS_BREL = 6 * P_SZ;
constexpr int WS_PRF  = WS_BREL + R * H;
constexpr int WS_PRB  = WS_PRF + R * H;
constexpr int WS_PGF  = WS_PRB + R * H;
constexpr int WS_PGB  = WS_PGF + B * H;
constexpr int WS_VF   = WS_PGB + B * H;      // (B,R,L) transposed scores
constexpr int WS_VB   = WS_VF + B * R * L;
constexpr int WS_CF   = WS_VB + B * R * L;   // (B,R,H)
constexpr int WS_CB   = WS_CF + B * R * H;
constexpr int WS_U    = WS_CB + B * R * H;   // 4 x (B*L)
constexpr int WS_CC   = WS_U + 4 * BL;       // 4 x (B*R)
constexpr int WS_SPAN = WS_CC + 4 * B * R;   // 16 ints

__device__ __forceinline__ float tanh_fast(float x) {
    // tanh(x) = 1 - 2/(1+e^{2x}); e^{2x} = 2^{x*2*log2(e)}
    float u = __builtin_amdgcn_exp2f(x * 2.8853900817779268f);
    return 1.0f - 2.0f * __builtin_amdgcn_rcpf(1.0f + u);
}

__device__ __forceinline__ float wave_sum(float v) {
    #pragma unroll
    for (int off = 32; off; off >>= 1) v += __shfl_down(v, off);
    return v;
}

// ---- boundary heads: f_hs, f_he, b_ts, b_te (exact fp32 — sign drives span logic)
__global__ __launch_bounds__(256) void k_boundary(const float* __restrict__ tok,
                                                  const float* __restrict__ fcw,
                                                  const float* __restrict__ fcb,
                                                  float* __restrict__ out) {
    int wid = blockIdx.x * 4 + (threadIdx.x >> 6);
    int lane = threadIdx.x & 63;
    int b = wid >> 7, l = wid & 127;
    const float* tr = tok + (b * L + l) * H;
    float p0 = 0, p1 = 0, p4 = 0, p5 = 0;
    #pragma unroll
    for (int j = 0; j < H / 64; ++j) {
        int h = lane + j * 64;
        float t = tr[h];
        p0 += t * fcw[h];
        p1 += t * fcw[H + h];
        p4 += t * fcw[4 * H + h];
        p5 += t * fcw[5 * H + h];
    }
    p0 = wave_sum(p0); p1 = wave_sum(p1); p4 = wave_sum(p4); p5 = wave_sum(p5);
    if (lane == 0) {
        int idx = b * L + l;
        out[OUT_FHS + idx] = p0 + fcb[0];
        out[OUT_FHE + idx] = p1 + fcb[1];
        out[OUT_BTS + idx] = p4 + fcb[4];
        out[OUT_BTE + idx] = p5 + fcb[5];
    }
}

// ---- span extraction (exact reference semantics): sigmoid(x)>0.5 <=> x>0
__global__ void k_span(const float* __restrict__ out, float* __restrict__ ws) {
    int t = threadIdx.x;
    if (t >= 8) return;
    int b = t & 3, ctx = t >> 2;
    const float* sp = out + (ctx ? OUT_BTS : OUT_FHS) + b * L;
    const float* ep = out + (ctx ? OUT_BTE : OUT_FHE) + b * L;
    int s = -1;
    for (int l = 0; l < L; ++l) if (sp[l] > 0.f) { s = l; break; }
    int len;
    if (s < 0) { s = 0; len = 0; }
    else {
        int e = -1;
        for (int l = s; l < L; ++l) if (ep[l] > 0.f) { e = l; break; }
        if (e < 0) e = s;
        len = e - s + 1;
    }
    int* span = (int*)(ws + WS_SPAN);
    span[ctx * 8 + b] = s;
    span[ctx * 8 + 4 + b] = len;
}

// ---- b_rel_embs = b_rel_transe(48,100) @ r_proj_w(100,768) + r_proj_b
__global__ __launch_bounds__(256) void k_brel(const float* __restrict__ bt,
                                              const float* __restrict__ pw,
                                              const float* __restrict__ pb,
                                              float* __restrict__ outp) {
    __shared__ float s_a[D];
    int r = blockIdx.x;
    if (threadIdx.x < D) s_a[threadIdx.x] = bt[r * D + threadIdx.x];
    __syncthreads();
    #pragma unroll
    for (int jj = 0; jj < 3; ++jj) {
        int h = threadIdx.x + jj * 256;
        float acc = pb[h];
        for (int k = 0; k < D; ++k) acc += s_a[k] * pw[k * H + h];
        outp[r * H + h] = acc;
    }
}

// ---- batched GEMM: O = A(M,768) @ W(768,768) + bias, 10 problems
struct GemmDesc { const float* A; const float* W; const float* bias; float* O; int M; };
struct GemmArgs { GemmDesc d[10]; };

__global__ __launch_bounds__(256) void k_gemm(GemmArgs args) {
    GemmDesc dd = args.d[blockIdx.z];
    int m0 = blockIdx.y * 64;
    if (m0 >= dd.M) return;
    int n0 = blockIdx.x * 64;
    __shared__ __align__(16) float As[16][68];   // [k][m], pad to break conflicts
    __shared__ __align__(16) float Bs[16][64];   // [k][n]
    int tid = threadIdx.x;
    int tx = tid & 15, ty = tid >> 4;
    int a_m = tid >> 2, a_k = (tid & 3) * 4;
    int b_k = tid >> 4, b_n = (tid & 15) * 4;
    float acc[4][4] = {};
    for (int k0 = 0; k0 < H; k0 += 16) {
        float4 av = make_float4(0.f, 0.f, 0.f, 0.f);
        int row = m0 + a_m;
        if (row < dd.M) av = *(const float4*)&dd.A[row * H + k0 + a_k];
        As[a_k + 0][a_m] = av.x;
        As[a_k + 1][a_m] = av.y;
        As[a_k + 2][a_m] = av.z;
        As[a_k + 3][a_m] = av.w;
        *(float4*)&Bs[b_k][b_n] = *(const float4*)&dd.W[(k0 + b_k) * H + n0 + b_n];
        __syncthreads();
        #pragma unroll
        for (int kk = 0; kk < 16; ++kk) {
            float4 a4 = *(const float4*)&As[kk][ty * 4];
            float4 b4 = *(const float4*)&Bs[kk][tx * 4];
            float aa[4] = {a4.x, a4.y, a4.z, a4.w};
            float bb[4] = {b4.x, b4.y, b4.z, b4.w};
            #pragma unroll
            for (int i = 0; i < 4; ++i)
                #pragma unroll
                for (int j = 0; j < 4; ++j)
                    acc[i][j] += aa[i] * bb[j];
        }
        __syncthreads();
    }
    float4 bias4 = *(const float4*)&dd.bias[n0 + tx * 4];
    float bb[4] = {bias4.x, bias4.y, bias4.z, bias4.w};
    #pragma unroll
    for (int i = 0; i < 4; ++i) {
        int row = m0 + ty * 4 + i;
        if (row < dd.M) {
            float4 o;
            o.x = acc[i][0] + bb[0];
            o.y = acc[i][1] + bb[1];
            o.z = acc[i][2] + bb[2];
            o.w = acc[i][3] + bb[3];
            *(float4*)&dd.O[row * H + n0 + tx * 4] = o;
        }
    }
}

// ---- attention scores: v[b,r,l] = sum_h tanh(px+pg+pr)*vw + vb  (stored (B,R,L))
__global__ __launch_bounds__(256) void k_attn_v(float* __restrict__ ws,
                                                const float* __restrict__ fcw,
                                                const float* __restrict__ fcb) {
    int ctx = blockIdx.y;
    int bl = blockIdx.x;
    int b = bl >> 7, l = bl & 127;
    const float* px = ws + (ctx ? 3 : 2) * P_SZ + bl * H;   // P2=tok@W4+bb4, P3=tok@W7+bb7
    const float* pg = ws + (ctx ? WS_PGB : WS_PGF) + b * H;
    const float* pr = ws + (ctx ? WS_PRB : WS_PRF);
    float* vout = ws + (ctx ? WS_VB : WS_VF);
    __shared__ float s_x[H];
    __shared__ float s_vw[H];
    for (int idx = threadIdx.x; idx < H; idx += 256) {
        s_x[idx] = px[idx] + pg[idx];
        s_vw[idx] = fcw[8 * H + idx];
    }
    __syncthreads();
    int w = threadIdx.x >> 6, lane = threadIdx.x & 63;
    float vb = fcb[8];
    for (int r = w; r < R; r += 4) {
        const float* prr = pr + r * H;
        float p = 0.f;
        #pragma unroll
        for (int j = 0; j < H / 64; ++j) {
            int h = lane + j * 64;
            p += tanh_fast(s_x[h] + prr[h]) * s_vw[h];
        }
        p = wave_sum(p);
        if (lane == 0) vout[(b * R + r) * L + l] = p + vb;
    }
}

// ---- softmax over L, in place on (B,R,L) rows (384 rows total, wave per row)
__global__ __launch_bounds__(256) void k_softmax(float* __restrict__ ws) {
    int row = blockIdx.x * 4 + (threadIdx.x >> 6);   // 0..383
    int lane = threadIdx.x & 63;
    float* base = ws + (row >= 192 ? WS_VB + (row - 192) * L : WS_VF + row * L);
    float x0 = base[lane], x1 = base[lane + 64];
    float m = fmaxf(x0, x1);
    #pragma unroll
    for (int off = 32; off; off >>= 1) m = fmaxf(m, __shfl_xor(m, off));
    constexpr float LOG2E = 1.4426950408889634f;
    float e0 = __builtin_amdgcn_exp2f((x0 - m) * LOG2E);
    float e1 = __builtin_amdgcn_exp2f((x1 - m) * LOG2E);
    float s = e0 + e1;
    #pragma unroll
    for (int off = 32; off; off >>= 1) s += __shfl_xor(s, off);
    float inv = __builtin_amdgcn_rcpf(s);
    base[lane] = e0 * inv;
    base[lane + 64] = e1 * inv;
}

// ---- C[b,r,h] = sum_l A[b,r,l] * tok[b,l,h]
__global__ __launch_bounds__(256) void k_ctx(const float* __restrict__ tok, float* __restrict__ ws) {
    int r = blockIdx.x, b = blockIdx.y, ctx = blockIdx.z;
    const float* Arow = ws + (ctx ? WS_VB : WS_VF) + (b * R + r) * L;
    float* Cout = ws + (ctx ? WS_CB : WS_CF) + (b * R + r) * H;
    __shared__ float s_a[L];
    if (threadIdx.x < L) s_a[threadIdx.x] = Arow[threadIdx.x];
    __syncthreads();
    float a0 = 0, a1 = 0, a2 = 0;
    const float* tb = tok + b * L * H;
    for (int l = 0; l < L; ++l) {
        float a = s_a[l];
        const float* tp = tb + l * H;
        a0 += a * tp[threadIdx.x];
        a1 += a * tp[threadIdx.x + 256];
        a2 += a * tp[threadIdx.x + 512];
    }
    Cout[threadIdx.x] = a0;
    Cout[threadIdx.x + 256] = a1;
    Cout[threadIdx.x + 512] = a2;
}

// ---- u[b,l] = (Hik + tok) @ fc_w[k] for the 4 heads; Hik never materialized.
// f_h_w row = mask * P0[b, fs+l, :] (P0 includes bias bb0); f_Hik = f_h_w + P4 (has bb8)
__global__ __launch_bounds__(256) void k_udots(const float* __restrict__ tok,
                                               const float* __restrict__ fcw,
                                               float* __restrict__ ws) {
    int wid = blockIdx.x * 4 + (threadIdx.x >> 6);
    int lane = threadIdx.x & 63;
    int b = wid >> 7, l = wid & 127;
    const int* span = (const int*)(ws + WS_SPAN);
    int fs = span[b], flen = span[4 + b];
    int bs = span[8 + b], blen = span[12 + b];
    bool fm = l < flen, bm = l < blen;
    float fmf = fm ? 1.f : 0.f, bmf = bm ? 1.f : 0.f;
    const float* tr = tok + (b * L + l) * H;
    const float* p4r = ws + 4 * P_SZ + (b * L + l) * H;            // tok@W8+bb8
    const float* p5r = ws + 5 * P_SZ + (b * L + l) * H;            // tok@W9+bb9
    const float* g0r = ws + 0 * P_SZ + (b * L + (fm ? fs + l : 0)) * H;
    const float* g1r = ws + 1 * P_SZ + (b * L + (bm ? bs + l : 0)) * H;
    float pf2 = 0, pf3 = 0, pb6 = 0, pb7 = 0;
    #pragma unroll
    for (int j = 0; j < H / 64; ++j) {
        int h = lane + j * 64;
        float t = tr[h];
        float sf = t + p4r[h] + fmf * g0r[h];
        float sb = t + p5r[h] + bmf * g1r[h];
        pf2 += sf * fcw[2 * H + h];
        pf3 += sf * fcw[3 * H + h];
        pb6 += sb * fcw[6 * H + h];
        pb7 += sb * fcw[7 * H + h];
    }
    pf2 = wave_sum(pf2); pf3 = wave_sum(pf3);
    pb6 = wave_sum(pb6); pb7 = wave_sum(pb7);
    if (lane == 0) {
        int idx = b * L + l;
        float* u = ws + WS_U;
        u[idx] = pf2; u[BL + idx] = pf3; u[2 * BL + idx] = pb6; u[3 * BL + idx] = pb7;
    }
}

// ---- c[b,r] = C @ fc_w[k] for the 4 heads
__global__ __launch_bounds__(256) void k_cdots(const float* __restrict__ fcw, float* __restrict__ ws) {
    int row = blockIdx.x * 4 + (threadIdx.x >> 6); // 0..383
    int lane = threadIdx.x & 63;
    int ctx = row >= 192 ? 1 : 0;
    int rr = row - ctx * 192;
    const float* Crow = ws + (ctx ? WS_CB : WS_CF) + rr * H;
    const float* wA = fcw + (ctx ? 6 : 2) * H;
    const float* wB2 = fcw + (ctx ? 7 : 3) * H;
    float pa = 0, pb2 = 0;
    #pragma unroll
    for (int j = 0; j < H / 64; ++j) {
        int h = lane + j * 64;
        float cv = Crow[h];
        pa += cv * wA[h];
        pb2 += cv * wB2[h];
    }
    pa = wave_sum(pa); pb2 = wave_sum(pb2);
    if (lane == 0) {
        float* c = ws + WS_CC;
        c[(ctx * 2) * 192 + rr] = pa;
        c[(ctx * 2 + 1) * 192 + rr] = pb2;
    }
}

// ---- final broadcast: out[b,l,r] = u[b,l] + c[b,r] + fc_b[k]
__global__ __launch_bounds__(256) void k_bcast(const float* __restrict__ fcb,
                                               const float* __restrict__ ws,
                                               float* __restrict__ out) {
    int t = blockIdx.x * 256 + threadIdx.x;     // < 98304
    int head = t / 24576;
    int rem = t - head * 24576;
    int b = rem / 6144;
    int lr = rem - b * 6144;
    int l = lr / 48;
    int r = lr - l * 48;
    const int out_off[4] = {OUT_FTS, OUT_FTE, OUT_BHS, OUT_BHE};
    const int wb[4] = {2, 3, 6, 7};
    const float* u = ws + WS_U;
    const float* c = ws + WS_CC;
    out[out_off[head] + rem] = u[head * BL + b * L + l] + c[head * 192 + b * R + r] + fcb[wb[head]];
}

extern "C" void kernel_launch(void* const* d_in, const int* in_sizes, int n_in,
                              void* d_out, int out_size, void* d_ws, size_t ws_size,
                              hipStream_t stream) {
    const float* h_gs  = (const float*)d_in[0];
    const float* tok   = (const float*)d_in[1];
    const float* f_rel = (const float*)d_in[2];
    const float* b_rt  = (const float*)d_in[3];
    const float* rpw   = (const float*)d_in[4];
    const float* rpb   = (const float*)d_in[5];
    const float* fcw   = (const float*)d_in[6];
    const float* fcb   = (const float*)d_in[7];
    const float* bigw  = (const float*)d_in[8];
    const float* bigb  = (const float*)d_in[9];
    float* out = (float*)d_out;
    float* ws  = (float*)d_ws;

    k_boundary<<<128, 256, 0, stream>>>(tok, fcw, fcb, out);
    k_span<<<1, 64, 0, stream>>>(out, ws);
    k_brel<<<48, 256, 0, stream>>>(b_rt, rpw, rpb, ws + WS_BREL);

    GemmArgs ga;
    const int wj[6] = {0, 1, 4, 7, 8, 9};
    for (int j = 0; j < 6; ++j)
        ga.d[j] = GemmDesc{tok, bigw + (size_t)wj[j] * H * H, bigb + wj[j] * H,
                           ws + (size_t)j * P_SZ, BL};
    ga.d[6] = GemmDesc{f_rel,        bigw + 2 * (size_t)H * H, bigb + 2 * H, ws + WS_PRF, R};
    ga.d[7] = GemmDesc{ws + WS_BREL, bigw + 5 * (size_t)H * H, bigb + 5 * H, ws + WS_PRB, R};
    ga.d[8] = GemmDesc{h_gs,         bigw + 3 * (size_t)H * H, bigb + 3 * H, ws + WS_PGF, B};
    ga.d[9] = GemmDesc{h_gs,         bigw + 6 * (size_t)H * H, bigb + 6 * H, ws + WS_PGB, B};
    k_gemm<<<dim3(12, 8, 10), 256, 0, stream>>>(ga);

    k_attn_v<<<dim3(512, 2), 256, 0, stream>>>(ws, fcw, fcb);
    k_softmax<<<96, 256, 0, stream>>>(ws);
    k_ctx<<<dim3(48, 4, 2), 256, 0, stream>>>(tok, ws);
    k_udots<<<128, 256, 0, stream>>>(tok, fcw, ws);
    k_cdots<<<96, 256, 0, stream>>>(fcw, ws);
    k_bcast<<<384, 256, 0, stream>>>(fcb, ws, out);
}

// Round 2
// 150.161 us; speedup vs baseline: 1.4420x; 1.4420x over previous
//
#include <hip/hip_runtime.h>
#include <hip/hip_bf16.h>

constexpr int H = 768, B = 4, L = 128, R = 48, D = 100;
constexpr int BL = B * L;          // 512
constexpr int P_SZ = BL * H;       // 393216

// d_out offsets (floats)
constexpr int OUT_FHS = 0, OUT_FHE = 512, OUT_FTS = 1024, OUT_FTE = 25600,
              OUT_BTS = 50176, OUT_BTE = 50688, OUT_BHS = 51200, OUT_BHE = 75776;

// workspace offsets (floats). P order: j=0..5 -> big_w {0,1,4,7,8,9}
constexpr int WS_BREL = 6 * P_SZ;            // fp32 b_rel_embs (48,768)
constexpr int WS_PRF  = WS_BREL + R * H;
constexpr int WS_PRB  = WS_PRF + R * H;
constexpr int WS_PGF  = WS_PRB + R * H;
constexpr int WS_PGB  = WS_PGF + B * H;
constexpr int WS_VF   = WS_PGB + B * H;      // (B,R,L) scores
constexpr int WS_VB   = WS_VF + B * R * L;
constexpr int WS_T2   = WS_VB + B * R * L;   // 4 x (B*L): tok . fc_w{2,3,6,7}
constexpr int WS_U    = WS_T2 + 4 * BL;      // 4 x (B*L)
constexpr int WS_CC   = WS_U + 4 * BL;       // 4 x (B*R)
constexpr int WS_SPAN = WS_CC + 4 * B * R;   // 16 ints
constexpr int WS_BF16 = WS_SPAN + 16;        // bf16 region (ushort* base), 16B aligned

// ushort offsets inside bf16 region
constexpr int UB_TOK  = 0;                    // 512x768
constexpr int UB_FREL = UB_TOK + BL * H;      // 48x768
constexpr int UB_BREL = UB_FREL + R * H;      // 48x768
constexpr int UB_HGS  = UB_BREL + R * H;      // 4x768
constexpr int UB_WT   = UB_HGS + B * H;       // 10 x [n][k] 768x768 transposed bf16

typedef __attribute__((ext_vector_type(8))) short short8;
typedef __attribute__((ext_vector_type(4))) float floatx4;

__device__ __forceinline__ float tanh_fast(float x) {
    float u = __builtin_amdgcn_exp2f(x * 2.8853900817779268f);
    return 1.0f - 2.0f * __builtin_amdgcn_rcpf(1.0f + u);
}

__device__ __forceinline__ float wave_sum(float v) {
    #pragma unroll
    for (int off = 32; off; off >>= 1) v += __shfl_down(v, off);
    return v;
}

__device__ __forceinline__ ushort f2bf(float x) {
    __hip_bfloat16 h = __float2bfloat16(x);
    return __builtin_bit_cast(ushort, h);
}

__device__ __forceinline__ ushort4 f2bf4(float4 v) {
    ushort4 u;
    u.x = f2bf(v.x); u.y = f2bf(v.y); u.z = f2bf(v.z); u.w = f2bf(v.w);
    return u;
}

// ---- fused setup: boundary+t2 dots | brel(+cast) | casts | W transpose-cast
__global__ __launch_bounds__(256) void k_setup(const float* __restrict__ tok,
                                               const float* __restrict__ h_gs,
                                               const float* __restrict__ f_rel,
                                               const float* __restrict__ b_rt,
                                               const float* __restrict__ rpw,
                                               const float* __restrict__ rpb,
                                               const float* __restrict__ fcw,
                                               const float* __restrict__ fcb,
                                               const float* __restrict__ bigw,
                                               float* __restrict__ out,
                                               float* __restrict__ ws) {
    __shared__ float lds[64 * 65];
    ushort* ub = (ushort*)(ws + WS_BF16);
    int blk = blockIdx.x, tid = threadIdx.x;

    if (blk < 128) {
        // boundary heads (exact fp32, same summation order as round 1) + t2 dots
        int wid = blk * 4 + (tid >> 6), lane = tid & 63;
        int b = wid >> 7, l = wid & 127;
        const float* tr = tok + (b * L + l) * H;
        float p0 = 0, p1 = 0, p2 = 0, p3 = 0, p4 = 0, p5 = 0, p6 = 0, p7 = 0;
        #pragma unroll
        for (int j = 0; j < H / 64; ++j) {
            int h = lane + j * 64;
            float t = tr[h];
            p0 += t * fcw[h];
            p1 += t * fcw[H + h];
            p4 += t * fcw[4 * H + h];
            p5 += t * fcw[5 * H + h];
            p2 += t * fcw[2 * H + h];
            p3 += t * fcw[3 * H + h];
            p6 += t * fcw[6 * H + h];
            p7 += t * fcw[7 * H + h];
        }
        p0 = wave_sum(p0); p1 = wave_sum(p1); p4 = wave_sum(p4); p5 = wave_sum(p5);
        p2 = wave_sum(p2); p3 = wave_sum(p3); p6 = wave_sum(p6); p7 = wave_sum(p7);
        if (lane == 0) {
            int idx = b * L + l;
            out[OUT_FHS + idx] = p0 + fcb[0];
            out[OUT_FHE + idx] = p1 + fcb[1];
            out[OUT_BTS + idx] = p4 + fcb[4];
            out[OUT_BTE + idx] = p5 + fcb[5];
            float* t2 = ws + WS_T2;
            t2[idx] = p2; t2[BL + idx] = p3; t2[2 * BL + idx] = p6; t2[3 * BL + idx] = p7;
        }
    } else if (blk < 176) {
        // b_rel_embs row (fp32 + bf16 cast)
        int r = blk - 128;
        if (tid < D) lds[tid] = b_rt[r * D + tid];
        __syncthreads();
        #pragma unroll
        for (int jj = 0; jj < 3; ++jj) {
            int h = tid + jj * 256;
            float acc = rpb[h];
            for (int k = 0; k < D; ++k) acc += lds[k] * rpw[k * H + h];
            ws[WS_BREL + r * H + h] = acc;
            ub[UB_BREL + r * H + h] = f2bf(acc);
        }
    } else if (blk < 200) {
        // tok -> bf16 (393216 elems / 24 blocks)
        int base = (blk - 176) * 16384;
        #pragma unroll
        for (int i = 0; i < 16; ++i) {
            int e = base + i * 1024 + tid * 4;
            float4 v = *(const float4*)&tok[e];
            *(ushort4*)&ub[UB_TOK + e] = f2bf4(v);
        }
    } else if (blk < 204) {
        // f_rel -> bf16 (36864 / 4 blocks)
        int base = (blk - 200) * 9216;
        #pragma unroll
        for (int i = 0; i < 9; ++i) {
            int e = base + i * 1024 + tid * 4;
            float4 v = *(const float4*)&f_rel[e];
            *(ushort4*)&ub[UB_FREL + e] = f2bf4(v);
        }
    } else if (blk == 204) {
        // h_gs -> bf16 (3072)
        #pragma unroll
        for (int i = 0; i < 3; ++i) {
            int e = i * 1024 + tid * 4;
            float4 v = *(const float4*)&h_gs[e];
            *(ushort4*)&ub[UB_HGS + e] = f2bf4(v);
        }
    } else {
        // big_w[j] (k,n) -> WT[j] (n,k) bf16, 64x64 tiles, 144 tiles per j
        int wb = blk - 205;
        int j = wb / 144, t = wb - j * 144;
        int kt = t / 12, nt = t - kt * 12;
        int k0 = kt * 64, n0 = nt * 64;
        const float* W = bigw + (size_t)j * H * H;
        ushort* WT = ub + UB_WT + (size_t)j * H * H;
        #pragma unroll
        for (int it = 0; it < 4; ++it) {
            int kk = (tid >> 4) + it * 16;
            int nn = (tid & 15) * 4;
            float4 v = *(const float4*)&W[(k0 + kk) * H + n0 + nn];
            lds[kk * 65 + nn + 0] = v.x;
            lds[kk * 65 + nn + 1] = v.y;
            lds[kk * 65 + nn + 2] = v.z;
            lds[kk * 65 + nn + 3] = v.w;
        }
        __syncthreads();
        #pragma unroll
        for (int it = 0; it < 4; ++it) {
            int nn = (tid >> 4) + it * 16;
            int kk = (tid & 15) * 4;
            float4 v;
            v.x = lds[(kk + 0) * 65 + nn];
            v.y = lds[(kk + 1) * 65 + nn];
            v.z = lds[(kk + 2) * 65 + nn];
            v.w = lds[(kk + 3) * 65 + nn];
            *(ushort4*)&WT[(n0 + nn) * H + k0 + kk] = f2bf4(v);
        }
    }
}

// ---- span extraction via ballot (sigmoid(x)>0.5 <=> x>0), 8 waves = 8 (ctx,b)
__global__ void k_span(const float* __restrict__ out, float* __restrict__ ws) {
    int w = threadIdx.x >> 6, lane = threadIdx.x & 63;
    int ctx = w >> 2, b = w & 3;
    const float* sp = out + (ctx ? OUT_BTS : OUT_FHS) + b * L;
    const float* ep = out + (ctx ? OUT_BTE : OUT_FHE) + b * L;
    unsigned long long s0 = __ballot(sp[lane] > 0.f);
    unsigned long long s1 = __ballot(sp[lane + 64] > 0.f);
    unsigned long long e0 = __ballot(ep[lane] > 0.f);
    unsigned long long e1 = __ballot(ep[lane + 64] > 0.f);
    if (lane == 0) {
        int s, len;
        if (s0 == 0 && s1 == 0) { s = 0; len = 0; }
        else {
            s = s0 ? __builtin_ctzll(s0) : 64 + __builtin_ctzll(s1);
            int e;
            if (s < 64) {
                unsigned long long m0 = (e0 >> s) << s;
                e = m0 ? __builtin_ctzll(m0) : (e1 ? 64 + __builtin_ctzll(e1) : s);
            } else {
                int s2 = s - 64;
                unsigned long long m1 = (e1 >> s2) << s2;
                e = m1 ? 64 + __builtin_ctzll(m1) : s;
            }
            len = e - s + 1;
        }
        int* span = (int*)(ws + WS_SPAN);
        span[ctx * 8 + b] = s;
        span[ctx * 8 + 4 + b] = len;
    }
}

// ---- all 10 GEMMs via bf16 MFMA 16x16x32; wave tile 32(m) x 64(n), no LDS
struct MfmaDesc { const ushort* A; const ushort* W; const float* bias; float* O; int M; };
struct MfmaArgs { MfmaDesc d[10]; int off[11]; };

__global__ __launch_bounds__(64) void k_mfma(MfmaArgs args) {
    int blk = blockIdx.x;
    int p = 0;
    while (p < 9 && blk >= args.off[p + 1]) ++p;
    MfmaDesc dd = args.d[p];
    int t = blk - args.off[p];
    int mt = t / 12, nt = t - mt * 12;
    int m0 = mt * 32, n0 = nt * 64;
    int lane = threadIdx.x;
    int lr = lane & 15, q = lane >> 4;
    int Mm1 = dd.M - 1;
    int r0 = min(m0 + lr, Mm1);
    int r1 = min(m0 + 16 + lr, Mm1);
    const ushort* a0p = dd.A + r0 * H + q * 8;
    const ushort* a1p = dd.A + r1 * H + q * 8;
    const ushort* bp  = dd.W + (n0 + lr) * H + q * 8;
    floatx4 acc[2][4] = {};
    #pragma unroll
    for (int k0 = 0; k0 < H; k0 += 32) {
        short8 a0 = *(const short8*)(a0p + k0);
        short8 a1 = *(const short8*)(a1p + k0);
        #pragma unroll
        for (int j = 0; j < 4; ++j) {
            short8 bf = *(const short8*)(bp + j * 16 * H + k0);
            acc[0][j] = __builtin_amdgcn_mfma_f32_16x16x32_bf16(a0, bf, acc[0][j], 0, 0, 0);
            acc[1][j] = __builtin_amdgcn_mfma_f32_16x16x32_bf16(a1, bf, acc[1][j], 0, 0, 0);
        }
    }
    #pragma unroll
    for (int j = 0; j < 4; ++j) {
        int col = n0 + j * 16 + lr;
        float bv = dd.bias[col];
        #pragma unroll
        for (int i = 0; i < 2; ++i) {
            int rowb = m0 + i * 16 + q * 4;
            #pragma unroll
            for (int r = 0; r < 4; ++r) {
                int row = rowb + r;
                if (row < dd.M) dd.O[row * H + col] = acc[i][j][r] + bv;
            }
        }
    }
}

// ---- attention scores: v[b,r,l] = sum_h tanh(px+pg+pr)*vw + vb  (stored (B,R,L))
__global__ __launch_bounds__(256) void k_attn_v(float* __restrict__ ws,
                                                const float* __restrict__ fcw,
                                                const float* __restrict__ fcb) {
    int ctx = blockIdx.y;
    int bl = blockIdx.x;
    int b = bl >> 7;
    const float* px = ws + (ctx ? 3 : 2) * P_SZ + bl * H;
    const float* pg = ws + (ctx ? WS_PGB : WS_PGF) + b * H;
    const float* pr = ws + (ctx ? WS_PRB : WS_PRF);
    float* vout = ws + (ctx ? WS_VB : WS_VF);
    __shared__ float s_x[H];
    __shared__ float s_vw[H];
    for (int idx = threadIdx.x; idx < H; idx += 256) {
        s_x[idx] = px[idx] + pg[idx];
        s_vw[idx] = fcw[8 * H + idx];
    }
    __syncthreads();
    int w = threadIdx.x >> 6, lane = threadIdx.x & 63;
    int l = bl & 127;
    float vb = fcb[8];
    for (int r = w; r < R; r += 4) {
        const float* prr = pr + r * H;
        float p = 0.f;
        #pragma unroll
        for (int j = 0; j < H / 64; ++j) {
            int h = lane + j * 64;
            p += tanh_fast(s_x[h] + prr[h]) * s_vw[h];
        }
        p = wave_sum(p);
        if (lane == 0) vout[(b * R + r) * L + l] = p + vb;
    }
}

// ---- softmax over L fused with c[b,r] = sum_l A * (tok.w) for both heads
__global__ __launch_bounds__(64) void k_attn2(float* __restrict__ ws) {
    int row = blockIdx.x;               // 0..383
    int lane = threadIdx.x;
    int ctx = row >= 192 ? 1 : 0;
    int rr = row - ctx * 192;
    int b = rr / R;
    const float* base = ws + (ctx ? WS_VB : WS_VF) + rr * L;
    float x0 = base[lane], x1 = base[lane + 64];
    float m = fmaxf(x0, x1);
    #pragma unroll
    for (int off = 32; off; off >>= 1) m = fmaxf(m, __shfl_xor(m, off));
    constexpr float LOG2E = 1.4426950408889634f;
    float e0 = __builtin_amdgcn_exp2f((x0 - m) * LOG2E);
    float e1 = __builtin_amdgcn_exp2f((x1 - m) * LOG2E);
    float s = e0 + e1;
    #pragma unroll
    for (int off = 32; off; off >>= 1) s += __shfl_xor(s, off);
    float inv = __builtin_amdgcn_rcpf(s);
    const float* tA = ws + WS_T2 + (ctx * 2 + 0) * BL + b * L;
    const float* tB = ws + WS_T2 + (ctx * 2 + 1) * BL + b * L;
    float pa = e0 * tA[lane] + e1 * tA[lane + 64];
    float pb = e0 * tB[lane] + e1 * tB[lane + 64];
    pa = wave_sum(pa); pb = wave_sum(pb);
    if (lane == 0) {
        float* c = ws + WS_CC;
        c[(ctx * 2 + 0) * 192 + rr] = pa * inv;
        c[(ctx * 2 + 1) * 192 + rr] = pb * inv;
    }
}

// ---- u[b,l] = (Hik + tok) @ fc_w[k] for the 4 heads; Hik never materialized
__global__ __launch_bounds__(256) void k_udots(const float* __restrict__ tok,
                                               const float* __restrict__ fcw,
                                               float* __restrict__ ws) {
    int wid = blockIdx.x * 4 + (threadIdx.x >> 6);
    int lane = threadIdx.x & 63;
    int b = wid >> 7, l = wid & 127;
    const int* span = (const int*)(ws + WS_SPAN);
    int fs = span[b], flen = span[4 + b];
    int bs = span[8 + b], blen = span[12 + b];
    bool fm = l < flen, bm = l < blen;
    float fmf = fm ? 1.f : 0.f, bmf = bm ? 1.f : 0.f;
    const float* tr = tok + (b * L + l) * H;
    const float* p4r = ws + 4 * P_SZ + (b * L + l) * H;
    const float* p5r = ws + 5 * P_SZ + (b * L + l) * H;
    const float* g0r = ws + 0 * P_SZ + (b * L + (fm ? fs + l : 0)) * H;
    const float* g1r = ws + 1 * P_SZ + (b * L + (bm ? bs + l : 0)) * H;
    float pf2 = 0, pf3 = 0, pb6 = 0, pb7 = 0;
    #pragma unroll
    for (int j = 0; j < H / 64; ++j) {
        int h = lane + j * 64;
        float t = tr[h];
        float sf = t + p4r[h] + fmf * g0r[h];
        float sb = t + p5r[h] + bmf * g1r[h];
        pf2 += sf * fcw[2 * H + h];
        pf3 += sf * fcw[3 * H + h];
        pb6 += sb * fcw[6 * H + h];
        pb7 += sb * fcw[7 * H + h];
    }
    pf2 = wave_sum(pf2); pf3 = wave_sum(pf3);
    pb6 = wave_sum(pb6); pb7 = wave_sum(pb7);
    if (lane == 0) {
        int idx = b * L + l;
        float* u = ws + WS_U;
        u[idx] = pf2; u[BL + idx] = pf3; u[2 * BL + idx] = pb6; u[3 * BL + idx] = pb7;
    }
}

// ---- final broadcast: out[b,l,r] = u[b,l] + c[b,r] + fc_b[k]
__global__ __launch_bounds__(256) void k_bcast(const float* __restrict__ fcb,
                                               const float* __restrict__ ws,
                                               float* __restrict__ out) {
    int t = blockIdx.x * 256 + threadIdx.x;     // < 98304
    int head = t / 24576;
    int rem = t - head * 24576;
    int b = rem / 6144;
    int lr = rem - b * 6144;
    int l = lr / 48;
    int r = lr - l * 48;
    const int out_off[4] = {OUT_FTS, OUT_FTE, OUT_BHS, OUT_BHE};
    const int wb[4] = {2, 3, 6, 7};
    const float* u = ws + WS_U;
    const float* c = ws + WS_CC;
    out[out_off[head] + rem] = u[head * BL + b * L + l] + c[head * 192 + b * R + r] + fcb[wb[head]];
}

extern "C" void kernel_launch(void* const* d_in, const int* in_sizes, int n_in,
                              void* d_out, int out_size, void* d_ws, size_t ws_size,
                              hipStream_t stream) {
    const float* h_gs  = (const float*)d_in[0];
    const float* tok   = (const float*)d_in[1];
    const float* f_rel = (const float*)d_in[2];
    const float* b_rt  = (const float*)d_in[3];
    const float* rpw   = (const float*)d_in[4];
    const float* rpb   = (const float*)d_in[5];
    const float* fcw   = (const float*)d_in[6];
    const float* fcb   = (const float*)d_in[7];
    const float* bigw  = (const float*)d_in[8];
    const float* bigb  = (const float*)d_in[9];
    float* out = (float*)d_out;
    float* ws  = (float*)d_ws;
    const ushort* ub = (const ushort*)(ws + WS_BF16);

    k_setup<<<1645, 256, 0, stream>>>(tok, h_gs, f_rel, b_rt, rpw, rpb, fcw, fcb, bigw, out, ws);
    k_span<<<1, 512, 0, stream>>>(out, ws);

    MfmaArgs ma;
    const int wj[6] = {0, 1, 4, 7, 8, 9};
    for (int j = 0; j < 6; ++j)
        ma.d[j] = MfmaDesc{ub + UB_TOK, ub + UB_WT + (size_t)wj[j] * H * H,
                           bigb + wj[j] * H, ws + (size_t)j * P_SZ, BL};
    ma.d[6] = MfmaDesc{ub + UB_FREL, ub + UB_WT + 2 * (size_t)H * H, bigb + 2 * H, ws + WS_PRF, R};
    ma.d[7] = MfmaDesc{ub + UB_BREL, ub + UB_WT + 5 * (size_t)H * H, bigb + 5 * H, ws + WS_PRB, R};
    ma.d[8] = MfmaDesc{ub + UB_HGS,  ub + UB_WT + 3 * (size_t)H * H, bigb + 3 * H, ws + WS_PGF, B};
    ma.d[9] = MfmaDesc{ub + UB_HGS,  ub + UB_WT + 6 * (size_t)H * H, bigb + 6 * H, ws + WS_PGB, B};
    // tiles: 16 m-tiles for M=512, 2 for M=48, 1 for M=4; 12 n-tiles each
    int off = 0;
    for (int p = 0; p < 10; ++p) {
        ma.off[p] = off;
        int mtiles = (ma.d[p].M + 31) / 32;
        off += mtiles * 12;
    }
    ma.off[10] = off;   // 1224
    k_mfma<<<off, 64, 0, stream>>>(ma);

    k_attn_v<<<dim3(512, 2), 256, 0, stream>>>(ws, fcw, fcb);
    k_attn2<<<384, 64, 0, stream>>>(ws);
    k_udots<<<128, 256, 0, stream>>>(tok, fcw, ws);
    k_bcast<<<384, 256, 0, stream>>>(fcb, ws, out);
}